// Round 16
// baseline (187.694 us; speedup 1.0000x reference)
//
#include <hip/hip_runtime.h>
#include <hip/hip_bf16.h>
#include <math.h>

// Problem constants: B=4, L=2048, D=1024, H=16, hd=64
// M = B*L = 8192, QKV N = 3072, proj N = 1024, K = 1024

typedef unsigned short u16;
typedef __attribute__((ext_vector_type(8))) short bf8;   // 8 bf16 = 4 VGPR (MFMA A/B frag, K=32)
typedef __attribute__((ext_vector_type(4))) short bf4;   // 4 bf16 = 2 VGPR
typedef __attribute__((ext_vector_type(4))) float f4;    // MFMA C/D frag

__device__ __forceinline__ u16 f2bf(float f) {
  unsigned int u = __float_as_uint(f);
  unsigned int r = (u + 0x7fffu + ((u >> 16) & 1u)) >> 16;
  return (u16)r;
}

__device__ __forceinline__ unsigned cvtpk_bf16(float lo, float hi) {
  unsigned r;
  asm("v_cvt_pk_bf16_f32 %0, %1, %2" : "=v"(r) : "v"(lo), "v"(hi));
  return r;
}

__device__ __forceinline__ f4 mfma16(bf8 a, bf8 b, f4 c) {
  return __builtin_amdgcn_mfma_f32_16x16x32_bf16(a, b, c, 0, 0, 0);
}

__device__ __forceinline__ float fexp2(float x) {
#if __has_builtin(__builtin_amdgcn_exp2f)
  return __builtin_amdgcn_exp2f(x);
#else
  return exp2f(x);
#endif
}

__device__ __forceinline__ void async_copy16(const void* gsrc, void* ldst) {
  __builtin_amdgcn_global_load_lds(
      (__attribute__((address_space(1))) void*)gsrc,
      (__attribute__((address_space(3))) void*)ldst,
      16, 0, 0);
}

// ---------------- prep kernels (fused -- proven R8-R15) ----------------

__global__ __launch_bounds__(256) void prep_k(const float* __restrict__ x,
                                              u16* __restrict__ xb,
                                              float* __restrict__ cosT,
                                              float* __restrict__ sinT) {
  int b = blockIdx.x;
  if (b < 8192) {
    int i = b * 256 + threadIdx.x;
    float4 v = ((const float4*)x)[i];
    ushort4 o;
    o.x = f2bf(v.x); o.y = f2bf(v.y); o.z = f2bf(v.z); o.w = f2bf(v.w);
    ((ushort4*)xb)[i] = o;
  } else {
    int i = (b - 8192) * 256 + threadIdx.x;  // 65536 = 2048 * 32
    int l = i >> 5, j = i & 31;
    float inv = powf(10000.0f, -(float)j / 32.0f);
    float f = (float)l * inv;
    cosT[i] = cosf(f);
    sinT[i] = sinf(f);
  }
}

__global__ __launch_bounds__(256) void transpose2_k(const float* __restrict__ qkv_w,
                                                    u16* __restrict__ wqkvT,
                                                    const float* __restrict__ proj_w,
                                                    u16* __restrict__ wprojT) {
  __shared__ float t[64][65];
  const int K = 1024;
  int y = blockIdx.y;
  const float* in; u16* out; int N;
  if (y < 48) { in = qkv_w; out = wqkvT; N = 3072; }
  else        { in = proj_w; out = wprojT; N = 1024; y -= 48; }
  int k0 = blockIdx.x * 64;
  int n0 = y * 64;
  int tx = threadIdx.x & 63, ty = threadIdx.x >> 6;
  for (int i = 0; i < 16; i++) {
    int r = ty + i * 4;
    t[r][tx] = in[(size_t)(k0 + r) * N + n0 + tx];
  }
  __syncthreads();
  for (int i = 0; i < 16; i++) {
    int r = ty + i * 4;
    out[(size_t)(n0 + r) * K + k0 + tx] = f2bf(t[tx][r]);
  }
}

// ---------------- GEMM (R2-exact K-loop + R10 epilogue; R11-R15-proven) ----------------
// 128x128 tile, BK=64, 4 waves (2x2). Single-buffered LDS (32KB, ~2.4 blocks/CU).
// Swizzle byte ^= ((row&7)<<4) on pre-swizzled global source and ds_read.
// EPI==1: Q pre-scaled by 0.125*log2(e); V stored kv-permuted (R11 notes).

template <int EPI>
__global__ __launch_bounds__(256, 2) void gemm_bt(
    const u16* __restrict__ A, const u16* __restrict__ Bt, const float* __restrict__ bias,
    float* __restrict__ outF,
    u16* __restrict__ Qb, u16* __restrict__ Kb, u16* __restrict__ Vt,
    const float* __restrict__ cosT, const float* __restrict__ sinT,
    int M, int N, int K) {
  __shared__ __attribute__((aligned(16))) u16 lA[128 * 64];
  __shared__ __attribute__((aligned(16))) u16 lB[128 * 64];
  const int tid = threadIdx.x;
  const int lane = tid & 63, wid = tid >> 6;
  const int nTilesN = N >> 7;
  const int bm = blockIdx.x / nTilesN, bn = blockIdx.x % nTilesN;
  const int m0 = bm << 7, n0 = bn << 7;
  const int wm = (wid >> 1) << 6, wn = (wid & 1) << 6;
  const int g = lane >> 4, c0 = lane & 15;

  f4 acc[4][4];
  for (int i = 0; i < 4; i++)
    for (int j = 0; j < 4; j++) acc[i][j] = (f4)0.0f;

  for (int k0 = 0; k0 < K; k0 += 64) {
    __syncthreads();
    for (int i = 0; i < 4; i++) {
      int chunk = i * 4 + wid;
      int p = chunk * 1024 + lane * 16;
      int row = p >> 7, pb = p & 127;
      int lb = pb ^ ((row & 7) << 4);
      async_copy16((const char*)(A + (size_t)(m0 + row) * K + k0) + lb,
                   (char*)lA + chunk * 1024);
    }
    for (int i = 0; i < 4; i++) {
      int chunk = i * 4 + wid;
      int p = chunk * 1024 + lane * 16;
      int row = p >> 7, pb = p & 127;
      int lb = pb ^ ((row & 7) << 4);
      async_copy16((const char*)(Bt + (size_t)(n0 + row) * K + k0) + lb,
                   (char*)lB + chunk * 1024);
    }
    __syncthreads();
    bf8 a[4][2], b[4][2];
    for (int ks = 0; ks < 2; ks++) {
      int cb = ks * 64 + g * 16;
      for (int mf = 0; mf < 4; mf++) {
        int row = wm + mf * 16 + c0;
        a[mf][ks] = *(const bf8*)((const char*)lA + (row << 7) + (cb ^ ((row & 7) << 4)));
      }
      for (int nf = 0; nf < 4; nf++) {
        int row = wn + nf * 16 + c0;
        b[nf][ks] = *(const bf8*)((const char*)lB + (row << 7) + (cb ^ ((row & 7) << 4)));
      }
    }
    for (int ks = 0; ks < 2; ks++)
      for (int mf = 0; mf < 4; mf++)
        for (int nf = 0; nf < 4; nf++)
          acc[mf][nf] = mfma16(a[mf][ks], b[nf][ks], acc[mf][nf]);
  }

  if (EPI == 0) {
    for (int nf = 0; nf < 4; nf++) {
      int col = n0 + wn + nf * 16 + c0;
      float bv = bias[col];
      for (int mf = 0; mf < 4; mf++) {
        int rowb = m0 + wm + mf * 16 + g * 4;
        for (int r = 0; r < 4; r++)
          outF[(size_t)(rowb + r) * N + col] = acc[mf][nf][r] + bv;
      }
    }
  } else {
    const int sec = n0 >> 10;
    const int h = (((n0 & 1023) + wn) >> 6);
    float bvs[4];
#pragma unroll
    for (int nf = 0; nf < 4; nf++) bvs[nf] = bias[n0 + wn + nf * 16 + c0];

    if (sec == 2) {
#pragma unroll
      for (int nf = 0; nf < 4; nf++) {
        int d = nf * 16 + c0;
        float bv = bvs[nf];
#pragma unroll
        for (int mf = 0; mf < 4; mf++) {
          int rowb = m0 + wm + mf * 16 + g * 4;
          int bb = rowb >> 11, l0 = rowb & 2047;
          int bh = bb * 16 + h;
          int lp = (l0 & ~31) | ((l0 & 16) >> 2) | ((l0 & 12) << 1);  // kv->c bit shuffle
          ushort4 o;
          o.x = f2bf(acc[mf][nf][0] + bv);
          o.y = f2bf(acc[mf][nf][1] + bv);
          o.z = f2bf(acc[mf][nf][2] + bv);
          o.w = f2bf(acc[mf][nf][3] + bv);
          *(ushort4*)&Vt[((size_t)bh * 64 + d) * 2048 + lp] = o;
        }
      }
    } else {
      u16* dst = (sec == 0) ? Qb : Kb;
      const float qs = (sec == 0) ? 0.18033688011112042f : 1.0f;  // 0.125*log2(e)
#pragma unroll
      for (int mf = 0; mf < 4; mf++) {
        int rowb = m0 + wm + mf * 16 + g * 4;
#pragma unroll
        for (int r = 0; r < 4; r++) {
          int row = rowb + r;
          int bb = row >> 11, l = row & 2047;
          int bh = bb * 16 + h;
          float cz0 = cosT[l * 32 + c0],      sz0 = sinT[l * 32 + c0];
          float cz1 = cosT[l * 32 + 16 + c0], sz1 = sinT[l * 32 + 16 + c0];
          float v0 = acc[mf][0][r] + bvs[0];
          float v1 = acc[mf][1][r] + bvs[1];
          float v2 = acc[mf][2][r] + bvs[2];
          float v3 = acc[mf][3][r] + bvs[3];
          size_t base = ((size_t)bh * 2048 + l) * 64;
          dst[base + c0]      = f2bf((v0 * cz0 - v2 * sz0) * qs);
          dst[base + 16 + c0] = f2bf((v1 * cz1 - v3 * sz1) * qs);
          dst[base + 32 + c0] = f2bf((v2 * cz0 + v0 * sz0) * qs);
          dst[base + 48 + c0] = f2bf((v3 * cz1 + v1 * sz1) * qs);
        }
      }
    }
  }
}

// ---------------- flash attention v10 (R14-exact inner loop + 3-blocks/CU geometry) ----------------
// CHANGE vs R14/R15: grid 512 paired-q-tile blocks -> 1024 SINGLE-q-tile blocks so
// 3 blocks/CU can be co-resident (R15 diagnosis: occupancy 18%, VALU 44% -- TLP-capped
// at 2 blocks/CU by grid size). LDS stays 48KB (3 buffers) = 3 blocks/CU;
// __launch_bounds__(256,3) keeps VGPR under the 3-waves/EU cap. QK-ahead pipeline
// DROPPED (needed 64KB LDS for only -2.4us; TLP gain dominates).
// Balance: qt = sawtooth(0,15,1,14,...) within each bh group -> mean work 17 steps
// everywhere, no heavy tail. XCD swizzle: 128 consecutive lblk (8 bh) per XCD ->
// K/V 4MB = one L2. Inner loop, softmax (lane-partial lrun), staging ledger: R14-EXACT
// (exit provably drained: stages <= nkt tiles, tail vmcnt(0) at kt=nkt-2).
__global__ __launch_bounds__(256, 3) void attn_fwd(
    const u16* __restrict__ Qb, const u16* __restrict__ Kb, const u16* __restrict__ Vt,
    u16* __restrict__ attnOut) {
  __shared__ __attribute__((aligned(16))) u16 kT[3][64 * 64];
  __shared__ __attribute__((aligned(16))) u16 vT[3][64 * 64];
  const int tid = threadIdx.x, lane = tid & 63, wid = tid >> 6;
  const int pblk = blockIdx.x;                 // nwg = 1024
  const int lblk = ((pblk & 7) << 7) | (pblk >> 3);   // XCD swizzle (1024 % 8 == 0)
  const int bh = lblk >> 4;                    // 0..63
  const int qtx = lblk & 15;
  const int qt = (qtx & 1) ? (15 - (qtx >> 1)) : (qtx >> 1);  // 0,15,1,14,... balanced
  const int bb = bh >> 4, h = bh & 15;
  const u16* Qp = Qb + (size_t)bh * 2048 * 64;
  const u16* Kp = Kb + (size_t)bh * 2048 * 64;
  const u16* Vp = Vt + (size_t)bh * 64 * 2048;   // [64 d][2048 l(permuted)]
  const int g = lane >> 4, c0 = lane & 15;

  auto stage = [&](int kt, int buf) {            // 4 copies: 2 K-chunks + 2 V-chunks
    int kv0 = kt * 64;
#pragma unroll
    for (int c = 0; c < 2; c++) {
      int off = c * 4096 + tid * 16;
      int row = off >> 7, pb = off & 127;
      int lb = pb ^ ((row & 7) << 4);
      async_copy16((const char*)(Kp + (size_t)(kv0 + row) * 64) + lb,
                   (char*)kT[buf] + off);
      async_copy16((const char*)(Vp + (size_t)row * 2048 + kv0) + lb,
                   (char*)vT[buf] + off);
    }
  };

  const int q0 = qt << 7;
  const int qw = q0 + wid * 32;

  bf8 qfr[2][2];
  for (int qf = 0; qf < 2; qf++)
    for (int ks = 0; ks < 2; ks++)
      qfr[qf][ks] = *(const bf8*)((const char*)Qp +
                                  (size_t)(qw + qf * 16 + c0) * 128 + ks * 64 + g * 16);

  f4 accO[2][4];
  for (int i = 0; i < 2; i++)
    for (int j = 0; j < 4; j++) accO[i][j] = (f4)0.0f;
  float mrun[2] = {-INFINITY, -INFINITY}, lrun[2] = {0.f, 0.f};

  const int nkt = (q0 >> 6) + 2;               // 2*qt + 2 steps
  stage(0, 0);
  stage(1, 1);
  asm volatile("s_waitcnt vmcnt(4)" ::: "memory");
  __builtin_amdgcn_s_barrier();

  for (int kt = 0; kt < nkt; ++kt) {
    if (kt + 2 < nkt) stage(kt + 2, (kt + 2) % 3);
    const char* kbuf = (const char*)kT[kt % 3];
    const char* vbuf = (const char*)vT[kt % 3];
    const int kv0 = kt * 64;

    // S^T = K Q^T (log2-scaled domain; Q pre-scaled)
    f4 s[2][4];
    for (int i = 0; i < 2; i++)
      for (int j = 0; j < 4; j++) s[i][j] = (f4)0.0f;
#pragma unroll
    for (int ks = 0; ks < 2; ks++) {
      int cb = ks * 64 + g * 16;
      bf8 kf[4];
#pragma unroll
      for (int kvf = 0; kvf < 4; kvf++) {
        int row = kvf * 16 + c0;
        kf[kvf] = *(const bf8*)(kbuf + (row << 7) + (cb ^ ((row & 7) << 4)));
      }
      __builtin_amdgcn_s_setprio(1);
#pragma unroll
      for (int kvf = 0; kvf < 4; kvf++)
#pragma unroll
        for (int qf = 0; qf < 2; qf++)
          s[qf][kvf] = mfma16(kf[kvf], qfr[qf][ks], s[qf][kvf]);
      __builtin_amdgcn_s_setprio(0);
    }

    // causal mask only on diagonal-straddling tiles
    if (kv0 + 63 > qw) {
#pragma unroll
      for (int qf = 0; qf < 2; qf++) {
        int q = qw + qf * 16 + c0;
#pragma unroll
        for (int kvf = 0; kvf < 4; kvf++)
#pragma unroll
          for (int r = 0; r < 4; r++) {
            int kv = kv0 + kvf * 16 + 4 * g + r;
            if (kv > q) s[qf][kvf][r] = -INFINITY;
          }
      }
    }

    // online softmax: lane-local tree-max gate; cross-lane reduce only on rescale;
    // lrun is LANE-PARTIAL (cross-lane summed once at write-out)
    bf4 pfrag[2][4];
#pragma unroll
    for (int qf = 0; qf < 2; qf++) {
      float t0 = fmaxf(fmaxf(s[qf][0][0], s[qf][0][1]), fmaxf(s[qf][0][2], s[qf][0][3]));
      float t1 = fmaxf(fmaxf(s[qf][1][0], s[qf][1][1]), fmaxf(s[qf][1][2], s[qf][1][3]));
      float t2 = fmaxf(fmaxf(s[qf][2][0], s[qf][2][1]), fmaxf(s[qf][2][2], s[qf][2][3]));
      float t3 = fmaxf(fmaxf(s[qf][3][0], s[qf][3][1]), fmaxf(s[qf][3][2], s[qf][3][3]));
      float lmx = fmaxf(fmaxf(t0, t1), fmaxf(t2, t3));
      if (__any(lmx > mrun[qf] + 8.0f)) {
        float mx = fmaxf(lmx, __shfl_xor(lmx, 16));
        mx = fmaxf(mx, __shfl_xor(mx, 32));
        float mn = fmaxf(mrun[qf], mx);
        float pc = fexp2(mrun[qf] - mn);
#pragma unroll
        for (int df = 0; df < 4; df++)
#pragma unroll
          for (int r = 0; r < 4; r++) accO[qf][df][r] *= pc;
        lrun[qf] *= pc;
        mrun[qf] = mn;
      }
      float m = mrun[qf];
      float ls = 0.f;
#pragma unroll
      for (int kvf = 0; kvf < 4; kvf++) {
        float p0 = fexp2(s[qf][kvf][0] - m);
        float p1 = fexp2(s[qf][kvf][1] - m);
        float p2 = fexp2(s[qf][kvf][2] - m);
        float p3 = fexp2(s[qf][kvf][3] - m);
        ls += (p0 + p1) + (p2 + p3);
        union { unsigned u[2]; bf4 v; } uu;
        uu.u[0] = cvtpk_bf16(p0, p1);
        uu.u[1] = cvtpk_bf16(p2, p3);
        pfrag[qf][kvf] = uu.v;
      }
      lrun[qf] += ls;   // lane-partial: no per-step shuffles
    }

    // O^T += V^T P^T at K=32 (permuted V, concat'd P)
#pragma unroll
    for (int kvp = 0; kvp < 2; kvp++) {
      bf8 vf[4];
      int cb = kvp * 64 + g * 16;
#pragma unroll
      for (int df = 0; df < 4; df++) {
        int row = df * 16 + c0;
        vf[df] = *(const bf8*)(vbuf + (row << 7) + (cb ^ ((row & 7) << 4)));
      }
      bf8 p8[2];
      p8[0] = __builtin_shufflevector(pfrag[0][2 * kvp], pfrag[0][2 * kvp + 1],
                                      0, 1, 2, 3, 4, 5, 6, 7);
      p8[1] = __builtin_shufflevector(pfrag[1][2 * kvp], pfrag[1][2 * kvp + 1],
                                      0, 1, 2, 3, 4, 5, 6, 7);
      __builtin_amdgcn_s_setprio(1);
#pragma unroll
      for (int df = 0; df < 4; df++)
#pragma unroll
        for (int qf = 0; qf < 2; qf++)
          accO[qf][df] = mfma16(vf[df], p8[qf], accO[qf][df]);
      __builtin_amdgcn_s_setprio(0);
    }

    if (kt + 2 < nkt)      asm volatile("s_waitcnt vmcnt(4)" ::: "memory");
    else if (kt + 1 < nkt) asm volatile("s_waitcnt vmcnt(0)" ::: "memory");
    __builtin_amdgcn_s_barrier();
  }

  // write out: cross-lane ls sum ONCE, then O^T regs -> attnOut [B*L][1024]
  for (int qf = 0; qf < 2; qf++) {
    float lt = lrun[qf];
    lt += __shfl_xor(lt, 16);
    lt += __shfl_xor(lt, 32);
    float inv = 1.0f / lt;
    int q = qw + qf * 16 + c0;
    for (int df = 0; df < 4; df++) {
      ushort4 o;
      o.x = f2bf(accO[qf][df][0] * inv);
      o.y = f2bf(accO[qf][df][1] * inv);
      o.z = f2bf(accO[qf][df][2] * inv);
      o.w = f2bf(accO[qf][df][3] * inv);
      int d = df * 16 + 4 * g;
      *(ushort4*)&attnOut[(size_t)(bb * 2048 + q) * 1024 + h * 64 + d] = o;
    }
  }
}

// ---------------- launch ----------------

extern "C" void kernel_launch(void* const* d_in, const int* in_sizes, int n_in,
                              void* d_out, int out_size, void* d_ws, size_t ws_size,
                              hipStream_t stream) {
  const float* x      = (const float*)d_in[0];
  const float* qkv_w  = (const float*)d_in[1];
  const float* qkv_b  = (const float*)d_in[2];
  const float* proj_w = (const float*)d_in[3];
  const float* proj_b = (const float*)d_in[4];
  float* out = (float*)d_out;

  char* ws = (char*)d_ws;
  u16* xb      = (u16*)ws;  ws += (size_t)8192 * 1024 * 2;
  u16* wqkvT   = (u16*)ws;  ws += (size_t)3072 * 1024 * 2;
  u16* wprojT  = (u16*)ws;  ws += (size_t)1024 * 1024 * 2;
  float* cosT  = (float*)ws; ws += (size_t)2048 * 32 * 4;
  float* sinT  = (float*)ws; ws += (size_t)2048 * 32 * 4;
  u16* Qb      = (u16*)ws;  ws += (size_t)64 * 2048 * 64 * 2;
  u16* Kb      = (u16*)ws;  ws += (size_t)64 * 2048 * 64 * 2;
  u16* Vt      = (u16*)ws;  ws += (size_t)64 * 2048 * 64 * 2;
  u16* attnOut = (u16*)ws;  ws += (size_t)8192 * 1024 * 2;
  // total ws usage ~92.3 MB

  prep_k<<<8448, 256, 0, stream>>>(x, xb, cosT, sinT);
  {
    dim3 tg(16, 64);
    transpose2_k<<<tg, 256, 0, stream>>>(qkv_w, wqkvT, proj_w, wprojT);
  }

  gemm_bt<1><<<64 * 24, 256, 0, stream>>>(xb, wqkvT, qkv_b, nullptr,
                                          Qb, Kb, Vt, cosT, sinT, 8192, 3072, 1024);
  attn_fwd<<<1024, 256, 0, stream>>>(Qb, Kb, Vt, attnOut);
  gemm_bt<0><<<64 * 8, 256, 0, stream>>>(attnOut, wprojT, proj_b, out,
                                         nullptr, nullptr, nullptr, nullptr, nullptr,
                                         8192, 1024, 1024);
}

// Round 17
// 156.792 us; speedup vs baseline: 1.1971x; 1.1971x over previous
//
#include <hip/hip_runtime.h>
#include <hip/hip_bf16.h>
#include <math.h>

// Problem constants: B=4, L=2048, D=1024, H=16, hd=64
// M = B*L = 8192, QKV N = 3072, proj N = 1024, K = 1024

typedef unsigned short u16;
typedef __attribute__((ext_vector_type(8))) short bf8;   // 8 bf16 = 4 VGPR (MFMA A/B frag, K=32)
typedef __attribute__((ext_vector_type(4))) short bf4;   // 4 bf16 = 2 VGPR
typedef __attribute__((ext_vector_type(4))) float f4;    // MFMA C/D frag

__device__ __forceinline__ u16 f2bf(float f) {
  unsigned int u = __float_as_uint(f);
  unsigned int r = (u + 0x7fffu + ((u >> 16) & 1u)) >> 16;
  return (u16)r;
}

__device__ __forceinline__ unsigned cvtpk_bf16(float lo, float hi) {
  unsigned r;
  asm("v_cvt_pk_bf16_f32 %0, %1, %2" : "=v"(r) : "v"(lo), "v"(hi));
  return r;
}

__device__ __forceinline__ f4 mfma16(bf8 a, bf8 b, f4 c) {
  return __builtin_amdgcn_mfma_f32_16x16x32_bf16(a, b, c, 0, 0, 0);
}

__device__ __forceinline__ float fexp2(float x) {
#if __has_builtin(__builtin_amdgcn_exp2f)
  return __builtin_amdgcn_exp2f(x);
#else
  return exp2f(x);
#endif
}

__device__ __forceinline__ void async_copy16(const void* gsrc, void* ldst) {
  __builtin_amdgcn_global_load_lds(
      (__attribute__((address_space(1))) void*)gsrc,
      (__attribute__((address_space(3))) void*)ldst,
      16, 0, 0);
}

// ---------------- prep kernels (fused -- proven R8-R16) ----------------

__global__ __launch_bounds__(256) void prep_k(const float* __restrict__ x,
                                              u16* __restrict__ xb,
                                              float* __restrict__ cosT,
                                              float* __restrict__ sinT) {
  int b = blockIdx.x;
  if (b < 8192) {
    int i = b * 256 + threadIdx.x;
    float4 v = ((const float4*)x)[i];
    ushort4 o;
    o.x = f2bf(v.x); o.y = f2bf(v.y); o.z = f2bf(v.z); o.w = f2bf(v.w);
    ((ushort4*)xb)[i] = o;
  } else {
    int i = (b - 8192) * 256 + threadIdx.x;  // 65536 = 2048 * 32
    int l = i >> 5, j = i & 31;
    float inv = powf(10000.0f, -(float)j / 32.0f);
    float f = (float)l * inv;
    cosT[i] = cosf(f);
    sinT[i] = sinf(f);
  }
}

__global__ __launch_bounds__(256) void transpose2_k(const float* __restrict__ qkv_w,
                                                    u16* __restrict__ wqkvT,
                                                    const float* __restrict__ proj_w,
                                                    u16* __restrict__ wprojT) {
  __shared__ float t[64][65];
  const int K = 1024;
  int y = blockIdx.y;
  const float* in; u16* out; int N;
  if (y < 48) { in = qkv_w; out = wqkvT; N = 3072; }
  else        { in = proj_w; out = wprojT; N = 1024; y -= 48; }
  int k0 = blockIdx.x * 64;
  int n0 = y * 64;
  int tx = threadIdx.x & 63, ty = threadIdx.x >> 6;
  for (int i = 0; i < 16; i++) {
    int r = ty + i * 4;
    t[r][tx] = in[(size_t)(k0 + r) * N + n0 + tx];
  }
  __syncthreads();
  for (int i = 0; i < 16; i++) {
    int r = ty + i * 4;
    out[(size_t)(n0 + r) * K + k0 + tx] = f2bf(t[tx][r]);
  }
}

// ---------------- GEMM (R2-exact K-loop + R10 epilogue; R11-R16-proven) ----------------
// 128x128 tile, BK=64, 4 waves (2x2). Single-buffered LDS (32KB, ~2.4 blocks/CU).
// Swizzle byte ^= ((row&7)<<4) on pre-swizzled global source and ds_read.
// EPI==1: Q pre-scaled by 0.125*log2(e); V stored kv-permuted (R11 notes).

template <int EPI>
__global__ __launch_bounds__(256, 2) void gemm_bt(
    const u16* __restrict__ A, const u16* __restrict__ Bt, const float* __restrict__ bias,
    float* __restrict__ outF,
    u16* __restrict__ Qb, u16* __restrict__ Kb, u16* __restrict__ Vt,
    const float* __restrict__ cosT, const float* __restrict__ sinT,
    int M, int N, int K) {
  __shared__ __attribute__((aligned(16))) u16 lA[128 * 64];
  __shared__ __attribute__((aligned(16))) u16 lB[128 * 64];
  const int tid = threadIdx.x;
  const int lane = tid & 63, wid = tid >> 6;
  const int nTilesN = N >> 7;
  const int bm = blockIdx.x / nTilesN, bn = blockIdx.x % nTilesN;
  const int m0 = bm << 7, n0 = bn << 7;
  const int wm = (wid >> 1) << 6, wn = (wid & 1) << 6;
  const int g = lane >> 4, c0 = lane & 15;

  f4 acc[4][4];
  for (int i = 0; i < 4; i++)
    for (int j = 0; j < 4; j++) acc[i][j] = (f4)0.0f;

  for (int k0 = 0; k0 < K; k0 += 64) {
    __syncthreads();
    for (int i = 0; i < 4; i++) {
      int chunk = i * 4 + wid;
      int p = chunk * 1024 + lane * 16;
      int row = p >> 7, pb = p & 127;
      int lb = pb ^ ((row & 7) << 4);
      async_copy16((const char*)(A + (size_t)(m0 + row) * K + k0) + lb,
                   (char*)lA + chunk * 1024);
    }
    for (int i = 0; i < 4; i++) {
      int chunk = i * 4 + wid;
      int p = chunk * 1024 + lane * 16;
      int row = p >> 7, pb = p & 127;
      int lb = pb ^ ((row & 7) << 4);
      async_copy16((const char*)(Bt + (size_t)(n0 + row) * K + k0) + lb,
                   (char*)lB + chunk * 1024);
    }
    __syncthreads();
    bf8 a[4][2], b[4][2];
    for (int ks = 0; ks < 2; ks++) {
      int cb = ks * 64 + g * 16;
      for (int mf = 0; mf < 4; mf++) {
        int row = wm + mf * 16 + c0;
        a[mf][ks] = *(const bf8*)((const char*)lA + (row << 7) + (cb ^ ((row & 7) << 4)));
      }
      for (int nf = 0; nf < 4; nf++) {
        int row = wn + nf * 16 + c0;
        b[nf][ks] = *(const bf8*)((const char*)lB + (row << 7) + (cb ^ ((row & 7) << 4)));
      }
    }
    for (int ks = 0; ks < 2; ks++)
      for (int mf = 0; mf < 4; mf++)
        for (int nf = 0; nf < 4; nf++)
          acc[mf][nf] = mfma16(a[mf][ks], b[nf][ks], acc[mf][nf]);
  }

  if (EPI == 0) {
    for (int nf = 0; nf < 4; nf++) {
      int col = n0 + wn + nf * 16 + c0;
      float bv = bias[col];
      for (int mf = 0; mf < 4; mf++) {
        int rowb = m0 + wm + mf * 16 + g * 4;
        for (int r = 0; r < 4; r++)
          outF[(size_t)(rowb + r) * N + col] = acc[mf][nf][r] + bv;
      }
    }
  } else {
    const int sec = n0 >> 10;
    const int h = (((n0 & 1023) + wn) >> 6);
    float bvs[4];
#pragma unroll
    for (int nf = 0; nf < 4; nf++) bvs[nf] = bias[n0 + wn + nf * 16 + c0];

    if (sec == 2) {
#pragma unroll
      for (int nf = 0; nf < 4; nf++) {
        int d = nf * 16 + c0;
        float bv = bvs[nf];
#pragma unroll
        for (int mf = 0; mf < 4; mf++) {
          int rowb = m0 + wm + mf * 16 + g * 4;
          int bb = rowb >> 11, l0 = rowb & 2047;
          int bh = bb * 16 + h;
          int lp = (l0 & ~31) | ((l0 & 16) >> 2) | ((l0 & 12) << 1);  // kv->c bit shuffle
          ushort4 o;
          o.x = f2bf(acc[mf][nf][0] + bv);
          o.y = f2bf(acc[mf][nf][1] + bv);
          o.z = f2bf(acc[mf][nf][2] + bv);
          o.w = f2bf(acc[mf][nf][3] + bv);
          *(ushort4*)&Vt[((size_t)bh * 64 + d) * 2048 + lp] = o;
        }
      }
    } else {
      u16* dst = (sec == 0) ? Qb : Kb;
      const float qs = (sec == 0) ? 0.18033688011112042f : 1.0f;  // 0.125*log2(e)
#pragma unroll
      for (int mf = 0; mf < 4; mf++) {
        int rowb = m0 + wm + mf * 16 + g * 4;
#pragma unroll
        for (int r = 0; r < 4; r++) {
          int row = rowb + r;
          int bb = row >> 11, l = row & 2047;
          int bh = bb * 16 + h;
          float cz0 = cosT[l * 32 + c0],      sz0 = sinT[l * 32 + c0];
          float cz1 = cosT[l * 32 + 16 + c0], sz1 = sinT[l * 32 + 16 + c0];
          float v0 = acc[mf][0][r] + bvs[0];
          float v1 = acc[mf][1][r] + bvs[1];
          float v2 = acc[mf][2][r] + bvs[2];
          float v3 = acc[mf][3][r] + bvs[3];
          size_t base = ((size_t)bh * 2048 + l) * 64;
          dst[base + c0]      = f2bf((v0 * cz0 - v2 * sz0) * qs);
          dst[base + 16 + c0] = f2bf((v1 * cz1 - v3 * sz1) * qs);
          dst[base + 32 + c0] = f2bf((v2 * cz0 + v0 * sz0) * qs);
          dst[base + 48 + c0] = f2bf((v3 * cz1 + v1 * sz1) * qs);
        }
      }
    }
  }
}

// ---------------- flash attention v11 (R16 inner loop + LPT dispatch order) ----------------
// R16 diagnosis: VALUBusy x duration is CONSERVED (~30us-equiv) => runtime = total VALU
// cycles / achieved concurrency. R16's interleaved qt order scattered long (32-step)
// blocks through the dispatch queue -> late-starting long blocks = low-occupancy tail
// (14.7%). FIX (mapping-only change; inner loop/ledger R14/R16-exact, passed twice):
// LPT order -- qt = 15 - (pblk>>6): all 64 longest blocks dispatch FIRST, descending.
// 768 of 1024 blocks resident at t=0 (3/CU LDS cap); short blocks backfill; makespan
// ~ max(32-step longest, 17408/768 ~ 22.7 avg) at up to 12 waves/CU (vs 8 in R15).
// XCD map: xcd = pblk&7, bh = (pblk&7)*8 + ((pblk>>3)&7) -> 8 bh per XCD (K/V 4MB = L2).
__global__ __launch_bounds__(256, 3) void attn_fwd(
    const u16* __restrict__ Qb, const u16* __restrict__ Kb, const u16* __restrict__ Vt,
    u16* __restrict__ attnOut) {
  __shared__ __attribute__((aligned(16))) u16 kT[3][64 * 64];
  __shared__ __attribute__((aligned(16))) u16 vT[3][64 * 64];
  const int tid = threadIdx.x, lane = tid & 63, wid = tid >> 6;
  const int pblk = blockIdx.x;                 // nwg = 1024
  const int bh = (pblk & 7) * 8 + ((pblk >> 3) & 7);   // 8 bh per XCD
  const int qt = 15 - (pblk >> 6);             // LPT: longest q-tiles dispatch first
  const int bb = bh >> 4, h = bh & 15;
  const u16* Qp = Qb + (size_t)bh * 2048 * 64;
  const u16* Kp = Kb + (size_t)bh * 2048 * 64;
  const u16* Vp = Vt + (size_t)bh * 64 * 2048;   // [64 d][2048 l(permuted)]
  const int g = lane >> 4, c0 = lane & 15;

  auto stage = [&](int kt, int buf) {            // 4 copies: 2 K-chunks + 2 V-chunks
    int kv0 = kt * 64;
#pragma unroll
    for (int c = 0; c < 2; c++) {
      int off = c * 4096 + tid * 16;
      int row = off >> 7, pb = off & 127;
      int lb = pb ^ ((row & 7) << 4);
      async_copy16((const char*)(Kp + (size_t)(kv0 + row) * 64) + lb,
                   (char*)kT[buf] + off);
      async_copy16((const char*)(Vp + (size_t)row * 2048 + kv0) + lb,
                   (char*)vT[buf] + off);
    }
  };

  const int q0 = qt << 7;
  const int qw = q0 + wid * 32;

  bf8 qfr[2][2];
  for (int qf = 0; qf < 2; qf++)
    for (int ks = 0; ks < 2; ks++)
      qfr[qf][ks] = *(const bf8*)((const char*)Qp +
                                  (size_t)(qw + qf * 16 + c0) * 128 + ks * 64 + g * 16);

  f4 accO[2][4];
  for (int i = 0; i < 2; i++)
    for (int j = 0; j < 4; j++) accO[i][j] = (f4)0.0f;
  float mrun[2] = {-INFINITY, -INFINITY}, lrun[2] = {0.f, 0.f};

  const int nkt = (q0 >> 6) + 2;               // 2*qt + 2 steps
  stage(0, 0);
  stage(1, 1);
  asm volatile("s_waitcnt vmcnt(4)" ::: "memory");
  __builtin_amdgcn_s_barrier();

  for (int kt = 0; kt < nkt; ++kt) {
    if (kt + 2 < nkt) stage(kt + 2, (kt + 2) % 3);
    const char* kbuf = (const char*)kT[kt % 3];
    const char* vbuf = (const char*)vT[kt % 3];
    const int kv0 = kt * 64;

    // S^T = K Q^T (log2-scaled domain; Q pre-scaled)
    f4 s[2][4];
    for (int i = 0; i < 2; i++)
      for (int j = 0; j < 4; j++) s[i][j] = (f4)0.0f;
#pragma unroll
    for (int ks = 0; ks < 2; ks++) {
      int cb = ks * 64 + g * 16;
      bf8 kf[4];
#pragma unroll
      for (int kvf = 0; kvf < 4; kvf++) {
        int row = kvf * 16 + c0;
        kf[kvf] = *(const bf8*)(kbuf + (row << 7) + (cb ^ ((row & 7) << 4)));
      }
      __builtin_amdgcn_s_setprio(1);
#pragma unroll
      for (int kvf = 0; kvf < 4; kvf++)
#pragma unroll
        for (int qf = 0; qf < 2; qf++)
          s[qf][kvf] = mfma16(kf[kvf], qfr[qf][ks], s[qf][kvf]);
      __builtin_amdgcn_s_setprio(0);
    }

    // causal mask only on diagonal-straddling tiles
    if (kv0 + 63 > qw) {
#pragma unroll
      for (int qf = 0; qf < 2; qf++) {
        int q = qw + qf * 16 + c0;
#pragma unroll
        for (int kvf = 0; kvf < 4; kvf++)
#pragma unroll
          for (int r = 0; r < 4; r++) {
            int kv = kv0 + kvf * 16 + 4 * g + r;
            if (kv > q) s[qf][kvf][r] = -INFINITY;
          }
      }
    }

    // online softmax: lane-local tree-max gate; cross-lane reduce only on rescale;
    // lrun is LANE-PARTIAL (cross-lane summed once at write-out)
    bf4 pfrag[2][4];
#pragma unroll
    for (int qf = 0; qf < 2; qf++) {
      float t0 = fmaxf(fmaxf(s[qf][0][0], s[qf][0][1]), fmaxf(s[qf][0][2], s[qf][0][3]));
      float t1 = fmaxf(fmaxf(s[qf][1][0], s[qf][1][1]), fmaxf(s[qf][1][2], s[qf][1][3]));
      float t2 = fmaxf(fmaxf(s[qf][2][0], s[qf][2][1]), fmaxf(s[qf][2][2], s[qf][2][3]));
      float t3 = fmaxf(fmaxf(s[qf][3][0], s[qf][3][1]), fmaxf(s[qf][3][2], s[qf][3][3]));
      float lmx = fmaxf(fmaxf(t0, t1), fmaxf(t2, t3));
      if (__any(lmx > mrun[qf] + 8.0f)) {
        float mx = fmaxf(lmx, __shfl_xor(lmx, 16));
        mx = fmaxf(mx, __shfl_xor(mx, 32));
        float mn = fmaxf(mrun[qf], mx);
        float pc = fexp2(mrun[qf] - mn);
#pragma unroll
        for (int df = 0; df < 4; df++)
#pragma unroll
          for (int r = 0; r < 4; r++) accO[qf][df][r] *= pc;
        lrun[qf] *= pc;
        mrun[qf] = mn;
      }
      float m = mrun[qf];
      float ls = 0.f;
#pragma unroll
      for (int kvf = 0; kvf < 4; kvf++) {
        float p0 = fexp2(s[qf][kvf][0] - m);
        float p1 = fexp2(s[qf][kvf][1] - m);
        float p2 = fexp2(s[qf][kvf][2] - m);
        float p3 = fexp2(s[qf][kvf][3] - m);
        ls += (p0 + p1) + (p2 + p3);
        union { unsigned u[2]; bf4 v; } uu;
        uu.u[0] = cvtpk_bf16(p0, p1);
        uu.u[1] = cvtpk_bf16(p2, p3);
        pfrag[qf][kvf] = uu.v;
      }
      lrun[qf] += ls;   // lane-partial: no per-step shuffles
    }

    // O^T += V^T P^T at K=32 (permuted V, concat'd P)
#pragma unroll
    for (int kvp = 0; kvp < 2; kvp++) {
      bf8 vf[4];
      int cb = kvp * 64 + g * 16;
#pragma unroll
      for (int df = 0; df < 4; df++) {
        int row = df * 16 + c0;
        vf[df] = *(const bf8*)(vbuf + (row << 7) + (cb ^ ((row & 7) << 4)));
      }
      bf8 p8[2];
      p8[0] = __builtin_shufflevector(pfrag[0][2 * kvp], pfrag[0][2 * kvp + 1],
                                      0, 1, 2, 3, 4, 5, 6, 7);
      p8[1] = __builtin_shufflevector(pfrag[1][2 * kvp], pfrag[1][2 * kvp + 1],
                                      0, 1, 2, 3, 4, 5, 6, 7);
      __builtin_amdgcn_s_setprio(1);
#pragma unroll
      for (int df = 0; df < 4; df++)
#pragma unroll
        for (int qf = 0; qf < 2; qf++)
          accO[qf][df] = mfma16(vf[df], p8[qf], accO[qf][df]);
      __builtin_amdgcn_s_setprio(0);
    }

    if (kt + 2 < nkt)      asm volatile("s_waitcnt vmcnt(4)" ::: "memory");
    else if (kt + 1 < nkt) asm volatile("s_waitcnt vmcnt(0)" ::: "memory");
    __builtin_amdgcn_s_barrier();
  }

  // write out: cross-lane ls sum ONCE, then O^T regs -> attnOut [B*L][1024]
  for (int qf = 0; qf < 2; qf++) {
    float lt = lrun[qf];
    lt += __shfl_xor(lt, 16);
    lt += __shfl_xor(lt, 32);
    float inv = 1.0f / lt;
    int q = qw + qf * 16 + c0;
    for (int df = 0; df < 4; df++) {
      ushort4 o;
      o.x = f2bf(accO[qf][df][0] * inv);
      o.y = f2bf(accO[qf][df][1] * inv);
      o.z = f2bf(accO[qf][df][2] * inv);
      o.w = f2bf(accO[qf][df][3] * inv);
      int d = df * 16 + 4 * g;
      *(ushort4*)&attnOut[(size_t)(bb * 2048 + q) * 1024 + h * 64 + d] = o;
    }
  }
}

// ---------------- launch ----------------

extern "C" void kernel_launch(void* const* d_in, const int* in_sizes, int n_in,
                              void* d_out, int out_size, void* d_ws, size_t ws_size,
                              hipStream_t stream) {
  const float* x      = (const float*)d_in[0];
  const float* qkv_w  = (const float*)d_in[1];
  const float* qkv_b  = (const float*)d_in[2];
  const float* proj_w = (const float*)d_in[3];
  const float* proj_b = (const float*)d_in[4];
  float* out = (float*)d_out;

  char* ws = (char*)d_ws;
  u16* xb      = (u16*)ws;  ws += (size_t)8192 * 1024 * 2;
  u16* wqkvT   = (u16*)ws;  ws += (size_t)3072 * 1024 * 2;
  u16* wprojT  = (u16*)ws;  ws += (size_t)1024 * 1024 * 2;
  float* cosT  = (float*)ws; ws += (size_t)2048 * 32 * 4;
  float* sinT  = (float*)ws; ws += (size_t)2048 * 32 * 4;
  u16* Qb      = (u16*)ws;  ws += (size_t)64 * 2048 * 64 * 2;
  u16* Kb      = (u16*)ws;  ws += (size_t)64 * 2048 * 64 * 2;
  u16* Vt      = (u16*)ws;  ws += (size_t)64 * 2048 * 64 * 2;
  u16* attnOut = (u16*)ws;  ws += (size_t)8192 * 1024 * 2;
  // total ws usage ~92.3 MB

  prep_k<<<8448, 256, 0, stream>>>(x, xb, cosT, sinT);
  {
    dim3 tg(16, 64);
    transpose2_k<<<tg, 256, 0, stream>>>(qkv_w, wqkvT, proj_w, wprojT);
  }

  gemm_bt<1><<<64 * 24, 256, 0, stream>>>(xb, wqkvT, qkv_b, nullptr,
                                          Qb, Kb, Vt, cosT, sinT, 8192, 3072, 1024);
  attn_fwd<<<1024, 256, 0, stream>>>(Qb, Kb, Vt, attnOut);
  gemm_bt<0><<<64 * 8, 256, 0, stream>>>(attnOut, wprojT, proj_b, out,
                                         nullptr, nullptr, nullptr, nullptr, nullptr,
                                         8192, 1024, 1024);
}